// Round 6
// baseline (58.587 us; speedup 1.0000x reference)
//
#include <hip/hip_runtime.h>

#define NB 1024
#define ND 256
#define APB 8              // anchors per block (i-group)
#define JCH 256            // j-chunk per block
#define NCH (NB/JCH)       // 4 chunks
#define NTHR 256
#define MARGINF 0.3f
#define BIGV 1e9f
#define D2R 0.017453292519943295f
#define HD2R 0.008726646259971648f

// haversine 'a' thresholds: sin^2(T/(2*6371000)) (validated rounds 1-4)
#define A_POS 3.8495040e-12f   // 25 m
#define A_NEG 6.1592064e-11f   // 100 m

__device__ __forceinline__ float d4(float4 a, float4 b, float acc) {
    return fmaf(a.x,b.x, fmaf(a.y,b.y, fmaf(a.z,b.z, fmaf(a.w,b.w, acc))));
}

// PHASE 0: partial pmax^2 (pos, max-reduced) / nmin^2 (neg, min-reduced)
// PHASE 1: partial semi-hard min^2 (min-reduced!), window from partP
template<int PHASE>
__global__ __launch_bounds__(NTHR, 2) void pair_kernel(
    const float* __restrict__ emb, const float* __restrict__ gps,
    float* __restrict__ partP, float* __restrict__ partN, float* __restrict__ partS)
{
    __shared__ float4 sbuf[2][2048];    // 64 KB double-buffered j-tile [256 rows][8 slots]
    __shared__ float  sSqA[APB];
    __shared__ float  sRed[4][16];

    const int tid  = threadIdx.x;
    const int lane = tid & 63;
    const int wave = tid >> 6;
    const int g    = blockIdx.x >> 2;    // i-group 0..127
    const int c    = blockIdx.x & 3;     // j-chunk 0..3
    const int i0   = g * APB;
    const int jbase = c * JCH;
    const int j    = jbase + tid;        // this thread's row
    const float4* __restrict__ emb4 = (const float4*)emb;

    // ---- anchor squared norms (once per block) ----
    {
        int a = tid >> 5, seg = tid & 31;
        float4 p0 = emb4[(i0+a)*64 + seg*2];
        float4 p1 = emb4[(i0+a)*64 + seg*2 + 1];
        float s = d4(p1,p1, d4(p0,p0, 0.f));
        #pragma unroll
        for (int off = 1; off < 32; off <<= 1) s += __shfl_xor(s, off);
        if (seg == 0) sSqA[a] = s;
    }

    // ---- gps masks ----
    unsigned posb = 0, negb = 0;
    {
        float2 gj = ((const float2*)gps)[j];
        float cj = cosf(gj.x * D2R);
        #pragma unroll
        for (int a = 0; a < APB; ++a) {
            float latA = gps[(i0+a)*2], lonA = gps[(i0+a)*2+1];   // uniform
            float cA = cosf(latA * D2R);
            float sla = sinf((gj.x - latA) * HD2R);
            float slo = sinf((gj.y - lonA) * HD2R);
            float hav = fmaf(sla, sla, (cA*cj)*(slo*slo));
            if ((hav < A_POS) && (j != i0 + a)) posb |= (1u << a);
            if (hav > A_NEG)                    negb |= (1u << a);
        }
    }

    // ---- staged dot-product loop ----
    float acc[APB] = {0,0,0,0,0,0,0,0};
    float sq = 0.f;
    float4 st[8];

    // prologue: load+write tile kt=0
    #pragma unroll
    for (int q = 0; q < 8; ++q) {
        int S = tid + 256*q, r = S >> 3, cc = S & 7;
        st[q] = emb4[(size_t)(jbase + r)*64 + 0*8 + cc];
    }
    #pragma unroll
    for (int q = 0; q < 8; ++q) {
        int S = tid + 256*q, r = S >> 3, cc = S & 7;
        sbuf[0][r*8 + (cc ^ (r & 7))] = st[q];
    }
    __syncthreads();

    #pragma unroll
    for (int kt = 0; kt < 8; ++kt) {
        if (kt < 7) {               // issue next tile's loads early (hide L2 latency)
            #pragma unroll
            for (int q = 0; q < 8; ++q) {
                int S = tid + 256*q, r = S >> 3, cc = S & 7;
                st[q] = emb4[(size_t)(jbase + r)*64 + (kt+1)*8 + cc];
            }
        }
        // compute on current buffer: own row (swizzled, conflict-free) x 8 anchors
        #pragma unroll
        for (int s = 0; s < 8; ++s) {
            float4 v = sbuf[kt & 1][tid*8 + (s ^ (tid & 7))];
            sq = d4(v, v, sq);
            #pragma unroll
            for (int a = 0; a < APB; ++a) {
                float4 av = emb4[(i0+a)*64 + kt*8 + s];   // uniform
                acc[a] = d4(v, av, acc[a]);
            }
        }
        if (kt < 7) {
            #pragma unroll
            for (int q = 0; q < 8; ++q) {
                int S = tid + 256*q, r = S >> 3, cc = S & 7;
                sbuf[(kt+1) & 1][r*8 + (cc ^ (r & 7))] = st[q];
            }
            __syncthreads();
        }
    }

    // ---- finalize d^2 and per-thread mask folds ----
    // reduction convention: idx<8 half is MAX-reduced, idx>=8 half is MIN-reduced
    float red[16];
    if (PHASE == 0) {
        #pragma unroll
        for (int a = 0; a < APB; ++a) {
            float d2 = sSqA[a] + sq - 2.f*acc[a];
            d2 = d2 > 0.f ? d2 : 0.f;
            red[a]   = (posb >> a & 1u) ? d2 : -1.f;    // pmax^2 (max half)
            red[8+a] = (negb >> a & 1u) ? d2 : BIGV;    // nmin^2 (min half)
        }
    } else {
        #pragma unroll
        for (int a = 0; a < APB; ++a) {
            float dap2 = fmaxf(fmaxf(partP[0*NB + i0+a], partP[1*NB + i0+a]),
                               fmaxf(partP[2*NB + i0+a], partP[3*NB + i0+a]));
            float lo2, hi2;
            if (dap2 < 0.f) { lo2 = -1.f; hi2 = -1.f; }
            else { float hb = sqrtf(dap2) + MARGINF; lo2 = dap2; hi2 = hb*hb; }
            float d2 = sSqA[a] + sq - 2.f*acc[a];
            d2 = d2 > 0.f ? d2 : 0.f;
            bool semi = (negb >> a & 1u) && (d2 > lo2) && (d2 < hi2);
            red[a]   = -1.f;                            // unused (max half)
            red[8+a] = semi ? d2 : BIGV;                // smin^2 (MIN half — bugfix)
        }
    }

    // ---- block reduction: idx<8 -> max, idx>=8 -> min ----
    #pragma unroll
    for (int off = 1; off < 64; off <<= 1) {
        #pragma unroll
        for (int a = 0; a < APB; ++a) {
            red[a]   = fmaxf(red[a],   __shfl_xor(red[a],   off));
            red[8+a] = fminf(red[8+a], __shfl_xor(red[8+a], off));
        }
    }
    __syncthreads();
    if (lane == 0) {
        #pragma unroll
        for (int v = 0; v < 16; ++v) sRed[wave][v] = red[v];
    }
    __syncthreads();
    if (wave == 0) {
        int w = lane >> 4, idx = lane & 15;
        float x = sRed[w][idx];
        float p = __shfl_xor(x, 16);
        x = (idx < 8) ? fmaxf(x, p) : fminf(x, p);
        p = __shfl_xor(x, 32);
        x = (idx < 8) ? fmaxf(x, p) : fminf(x, p);
        if (w == 0) {
            if (PHASE == 0) {
                if (idx < 8)       partP[c*NB + i0 + idx]     = x;
                else               partN[c*NB + i0 + idx - 8] = x;
            } else {
                if (idx >= 8)      partS[c*NB + i0 + idx - 8] = x;   // min half — bugfix
            }
        }
    }
}

__global__ __launch_bounds__(256) void finalize_kernel(
    const float* __restrict__ partP, const float* __restrict__ partN,
    const float* __restrict__ partS, float* __restrict__ out)
{
    const int tid = threadIdx.x;
    float st = 0.f, sv = 0.f;
    #pragma unroll
    for (int q = 0; q < 4; ++q) {
        int i = tid + 256*q;
        float dap2 = fmaxf(fmaxf(partP[i], partP[NB+i]), fmaxf(partP[2*NB+i], partP[3*NB+i]));
        float nm2  = fminf(fminf(partN[i], partN[NB+i]), fminf(partN[2*NB+i], partN[3*NB+i]));
        float sm2  = fminf(fminf(partS[i], partS[NB+i]), fminf(partS[2*NB+i], partS[3*NB+i]));
        bool has_pos  = dap2 > -0.5f;
        bool has_neg  = nm2 < 0.5f*BIGV;
        bool has_semi = sm2 < 0.5f*BIGV;
        float dap = has_pos ? sqrtf(dap2) : -1.f;
        float dan = sqrtf(has_semi ? sm2 : nm2);
        float t = dap - dan + MARGINF;
        t = t > 0.f ? t : 0.f;
        bool valid = has_pos && has_neg;
        st += valid ? t : 0.f;
        sv += valid ? 1.f : 0.f;
    }
    #pragma unroll
    for (int off = 1; off < 64; off <<= 1) {
        st += __shfl_xor(st, off);
        sv += __shfl_xor(sv, off);
    }
    __shared__ float rt[4], rv[4];
    if ((tid & 63) == 0) { rt[tid>>6] = st; rv[tid>>6] = sv; }
    __syncthreads();
    if (tid == 0) {
        float t = rt[0]+rt[1]+rt[2]+rt[3];
        float v = rv[0]+rv[1]+rv[2]+rv[3];
        out[0] = t / fmaxf(v, 1.f);
    }
}

extern "C" void kernel_launch(void* const* d_in, const int* in_sizes, int n_in,
                              void* d_out, int out_size, void* d_ws, size_t ws_size,
                              hipStream_t stream) {
    const float* emb = (const float*)d_in[0];   // [1024,256] f32
    const float* gps = (const float*)d_in[1];   // [1024,2]  f32
    float* partP = (float*)d_ws;                // [4][1024]
    float* partN = partP + NCH*NB;              // [4][1024]
    float* partS = partN + NCH*NB;              // [4][1024]
    pair_kernel<0><<<(NB/APB)*NCH, NTHR, 0, stream>>>(emb, gps, partP, partN, partS);
    pair_kernel<1><<<(NB/APB)*NCH, NTHR, 0, stream>>>(emb, gps, partP, partN, partS);
    finalize_kernel<<<1, 256, 0, stream>>>(partP, partN, partS, (float*)d_out);
}